// Round 1
// baseline (785.714 us; speedup 1.0000x reference)
//
#include <hip/hip_runtime.h>
#include <math.h>

static constexpr float kSigma = 3.5412f;
static constexpr float kMu    = -9.1232f;
static constexpr int   kRows  = 4096;   // 32*1*128
static constexpr int   kT     = 1024;
static constexpr float kTwoPi = 6.28318530717958647692f;

// One thread = one STFT frame. Samples (windowed, exp-unnormalized) held in
// registers (static indexing via full unroll; NFFT is a template constant).
// DFT per bin via rotating phasor: 8 FMA per (bin,k), zero LDS traffic.
template <int NFFT>
__global__ __launch_bounds__(256, 2)
void stft_loss_kernel(const float* __restrict__ xg,
                      const float* __restrict__ yg,
                      float* __restrict__ acc /* [3]: sum_d2, sum_y2, sum_log */)
{
    constexpr int HOP = NFFT / 4;
    constexpr int PAD = NFFT / 2;
    constexpr int B   = NFFT / 2 + 1;
    constexpr int F   = 1 + kT / HOP;   // frames per row

    const int fid = blockIdx.x * blockDim.x + threadIdx.x;

    float sd2 = 0.f, sy2 = 0.f, slg = 0.f;

    if (fid < kRows * F) {
        const int row = fid / F;          // F is constexpr -> magic-mul
        const int t   = fid - row * F;
        const float* __restrict__ xr = xg + row * kT;
        const float* __restrict__ yr = yg + row * kT;

        // Load + exp-unnormalize + Hann window. k=0 skipped (w[0]=0).
        float sx[NFFT], sy[NFFT];
        const int start = t * HOP - PAD;
#pragma unroll
        for (int k = 1; k < NFFT; ++k) {
            int i = start + k;
            i = (i < 0) ? -i : i;                         // reflect left
            i = (i > kT - 1) ? (2 * (kT - 1) - i) : i;    // reflect right
            const float w = 0.5f - 0.5f * __cosf((kTwoPi / NFFT) * (float)k);
            sx[k] = __expf(fmaf(xr[i], kSigma, kMu)) * w;
            sy[k] = __expf(fmaf(yr[i], kSigma, kMu)) * w;
        }

        // Per-bin DFT. Phasor q_k = e^{-2*pi*i*k*b/NFFT}; <=63 rotation steps,
        // drift ~1e-6 relative, negligible vs 4.4e-2 threshold.
#pragma unroll 1
        for (int b = 0; b < B; ++b) {
            float cb, sb;
            __sincosf((-kTwoPi / NFFT) * (float)b, &sb, &cb);
            float qc = cb, qs = sb;   // phasor at k=1
            float xre = 0.f, xim = 0.f, yre = 0.f, yim = 0.f;
#pragma unroll
            for (int k = 1; k < NFFT; ++k) {
                xre = fmaf(sx[k], qc, xre);
                xim = fmaf(sx[k], qs, xim);
                yre = fmaf(sy[k], qc, yre);
                yim = fmaf(sy[k], qs, yim);
                const float tq = qc * cb - qs * sb;   // rotate one step
                qs = fmaf(qs, cb, qc * sb);
                qc = tq;
            }
            const float mx = sqrtf(fmaf(xre, xre, xim * xim)) + 1e-7f;
            const float my = sqrtf(fmaf(yre, yre, yim * yim)) + 1e-7f;
            const float d  = my - mx;
            sd2 = fmaf(d, d, sd2);
            sy2 = fmaf(my, my, sy2);
            slg += fabsf(__logf(mx) - __logf(my));
        }
    }

    // Wave reduce (64 lanes), then cross-wave via LDS, 3 atomics per block.
#pragma unroll
    for (int off = 32; off > 0; off >>= 1) {
        sd2 += __shfl_down(sd2, off);
        sy2 += __shfl_down(sy2, off);
        slg += __shfl_down(slg, off);
    }
    __shared__ float red[3][4];
    const int wid  = threadIdx.x >> 6;
    const int lane = threadIdx.x & 63;
    if (lane == 0) { red[0][wid] = sd2; red[1][wid] = sy2; red[2][wid] = slg; }
    __syncthreads();
    if (threadIdx.x == 0) {
        atomicAdd(&acc[0], red[0][0] + red[0][1] + red[0][2] + red[0][3]);
        atomicAdd(&acc[1], red[1][0] + red[1][1] + red[1][2] + red[1][3]);
        atomicAdd(&acc[2], red[2][0] + red[2][1] + red[2][2] + red[2][3]);
    }
}

__global__ void finalize_kernel(const float* __restrict__ acc,
                                float* __restrict__ out)
{
    if (threadIdx.x == 0 && blockIdx.x == 0) {
        // elements per resolution: kRows * F * B
        const float nel[4] = {10506240.f, 9474048.f, 8982528.f, 8785920.f};
        float sc = 0.f, mg = 0.f;
#pragma unroll
        for (int r = 0; r < 4; ++r) {
            sc += sqrtf(acc[3 * r + 0]) / (sqrtf(acc[3 * r + 1]) + 1e-8f);
            mg += acc[3 * r + 2] / nel[r];
        }
        out[0] = sc * 0.25f;
        out[1] = mg * 0.25f;
    }
}

extern "C" void kernel_launch(void* const* d_in, const int* in_sizes, int n_in,
                              void* d_out, int out_size, void* d_ws, size_t ws_size,
                              hipStream_t stream)
{
    const float* x = (const float*)d_in[0];
    const float* y = (const float*)d_in[1];
    float* out = (float*)d_out;
    float* acc = (float*)d_ws;   // 12 floats: 4 resolutions x 3 sums

    hipMemsetAsync(acc, 0, 12 * sizeof(float), stream);

    // blocks = kRows * F / 256 (all exact multiples)
    stft_loss_kernel<8> <<<(kRows * 513 + 255) / 256, 256, 0, stream>>>(x, y, acc + 0);
    stft_loss_kernel<16><<<(kRows * 257 + 255) / 256, 256, 0, stream>>>(x, y, acc + 3);
    stft_loss_kernel<32><<<(kRows * 129 + 255) / 256, 256, 0, stream>>>(x, y, acc + 6);
    stft_loss_kernel<64><<<(kRows * 65  + 255) / 256, 256, 0, stream>>>(x, y, acc + 9);

    finalize_kernel<<<1, 64, 0, stream>>>(acc, out);
}

// Round 2
// 344.237 us; speedup vs baseline: 2.2825x; 2.2825x over previous
//
#include <hip/hip_runtime.h>
#include <math.h>

static constexpr float kSigma = 3.5412f;
static constexpr float kMu    = -9.1232f;
static constexpr int   kRows  = 4096;   // 32*1*128
static constexpr int   kT     = 1024;
static constexpr float kTwoPi = 6.28318530717958647692f;

// magnitude of Hann-windowed bin from rect-DFT neighbors:
// W[b] = 0.5*X[b] - 0.25*(X[b-1] + X[b+1])
__device__ __forceinline__ float wmag(float pmre, float pmim, float pcre, float pcim,
                                      float ppre, float ppim) {
    const float wre = 0.5f * pcre - 0.25f * (pmre + ppre);
    const float wim = 0.5f * pcim - 0.25f * (pmim + ppim);
    return sqrtf(fmaf(wre, wre, wim * wim)) + 1e-7f;
}

__device__ __forceinline__ void accum(float mx, float my,
                                      float& sd2, float& sy2, float& slg) {
    const float d = my - mx;
    sd2 = fmaf(d, d, sd2);
    sy2 = fmaf(my, my, sy2);
    slg += fabsf(__logf(__fdividef(mx, my)));
}

// Goertzel step: s1' = v - s2 + co*s1 ; s2' = s1   (co = 2cos(w))
#define GSTEP(s1, s2, co, v) { const float _t = (v) - s2; s2 = s1; s1 = fmaf(co, s2, _t); }

#define COEF4(BASE) \
    float cb0, sb0, cb1, sb1, cb2, sb2, cb3, sb3; \
    __sincosf((BASE) + STEP * 1.f, &sb0, &cb0); \
    __sincosf((BASE) + STEP * 2.f, &sb1, &cb1); \
    __sincosf((BASE) + STEP * 3.f, &sb2, &cb2); \
    __sincosf((BASE) + STEP * 4.f, &sb3, &cb3); \
    const float co0 = cb0 + cb0, co1 = cb1 + cb1, co2 = cb2 + cb2, co3 = cb3 + cb3;

#define BIN4_DECL \
    float s1x0=0,s2x0=0,s1y0=0,s2y0=0, s1x1=0,s2x1=0,s1y1=0,s2y1=0, \
          s1x2=0,s2x2=0,s1y2=0,s2y2=0, s1x3=0,s2x3=0,s1y3=0,s2y3=0;

#define BIN4_STEP(xv, yv) \
    GSTEP(s1x0, s2x0, co0, xv); GSTEP(s1y0, s2y0, co0, yv); \
    GSTEP(s1x1, s2x1, co1, xv); GSTEP(s1y1, s2y1, co1, yv); \
    GSTEP(s1x2, s2x2, co2, xv); GSTEP(s1y2, s2y2, co2, yv); \
    GSTEP(s1x3, s2x3, co3, xv); GSTEP(s1y3, s2y3, co3, yv);

// X[b] = e^{iw}*s1 - s2 -> re = s1*cos - s2, im = s1*sin
#define BIN4_EPI \
    const float n0xre = fmaf(s1x0, cb0, -s2x0), n0xim = s1x0 * sb0; \
    const float n0yre = fmaf(s1y0, cb0, -s2y0), n0yim = s1y0 * sb0; \
    const float n1xre = fmaf(s1x1, cb1, -s2x1), n1xim = s1x1 * sb1; \
    const float n1yre = fmaf(s1y1, cb1, -s2y1), n1yim = s1y1 * sb1; \
    const float n2xre = fmaf(s1x2, cb2, -s2x2), n2xim = s1x2 * sb2; \
    const float n2yre = fmaf(s1y2, cb2, -s2y2), n2yim = s1y2 * sb2; \
    const float n3xre = fmaf(s1x3, cb3, -s2x3), n3xim = s1x3 * sb3; \
    const float n3yre = fmaf(s1y3, cb3, -s2y3), n3yim = s1y3 * sb3;

#define KLOOP(...) \
    _Pragma("unroll 16") \
    for (int k = 0; k < NFFT; ++k) { \
        const int jj = sj + k; \
        const int a = jj + (jj >> 5); \
        const float xv = lx[a], yv = ly[a]; \
        __VA_ARGS__ \
        BIN4_STEP(xv, yv) \
    }

#define EMIT(pm, pc, pp) \
    accum(wmag(pm##xre, pm##xim, pc##xre, pc##xim, pp##xre, pp##xim), \
          wmag(pm##yre, pm##yim, pc##yre, pc##yim, pp##yre, pp##yim), sd2, sy2, slg)

#define SHIFT_H \
    h2xre = n2xre; h2xim = n2xim; h2yre = n2yre; h2yim = n2yim; \
    h1xre = n3xre; h1xim = n3xim; h1yre = n3yre; h1yim = n3yim;

template <int NFFT>
__global__ __launch_bounds__(256)
void stft_loss_kernel(const float* __restrict__ xg, const float* __restrict__ yg,
                      float* __restrict__ acc /* strided: [0],[64],[128] */)
{
    constexpr int HOP = NFFT / 4;
    constexpr int PAD = NFFT / 2;
    constexpr int F   = 1 + kT / HOP;          // frames per row
    constexpr int PL  = kT + NFFT;             // staged samples per row (j = i + PAD)
    constexpr int RSTRIDE = PL + PL / 32 + 2;  // +1 pad float per 32 -> <=2-way banks
    constexpr int RMAX = 255 / F + 2;          // rows a 256-frame block can span
    constexpr int NCH  = NFFT / 8;             // chunks of 4 Goertzel bins covering 1..N/2
    constexpr float STEP = kTwoPi / NFFT;

    __shared__ float lds[2][RMAX][RSTRIDE];
    __shared__ float red[3][4];

    const int tid  = threadIdx.x;
    const int B0   = blockIdx.x << 8;
    const int row0 = B0 / F;
    const int nrows = min(RMAX, kRows - row0);

    // ---- stage: exp-unnormalize + reflect-pad rows into padded LDS
    for (int t = tid; t < nrows * PL; t += 256) {
        const int rs = t / PL;
        const int j  = t - rs * PL;
        int i = j - PAD;
        i = (i < 0) ? -i : i;
        i = (i > kT - 1) ? (2 * (kT - 1) - i) : i;
        const int g = (row0 + rs) * kT + i;
        const int a = j + (j >> 5);
        lds[0][rs][a] = __expf(fmaf(xg[g], kSigma, kMu));
        lds[1][rs][a] = __expf(fmaf(yg[g], kSigma, kMu));
    }
    __syncthreads();

    // ---- compute: thread = frame
    const int fid = B0 + tid;                  // grid sized exactly: always valid
    const int row = fid / F;
    const int t   = fid - row * F;
    const float* __restrict__ lx = &lds[0][row - row0][0];
    const float* __restrict__ ly = &lds[1][row - row0][0];
    const int sj = t * HOP;                    // j of k=0 for this frame

    float sd2 = 0.f, sy2 = 0.f, slg = 0.f;
    float h1xre, h1xim, h2xre, h2xim, h1yre, h1yim, h2yre, h2yim;

    // ---- chunk 0: bin 0 (direct sum) + bins 1..4 (Goertzel)
    {
        COEF4(0.f)
        BIN4_DECL
        float s0x = 0.f, s0y = 0.f;
        KLOOP(s0x += xv; s0y += yv;)
        BIN4_EPI
        // W[0] = 0.5*X0 - 0.5*Re(X1), imag exactly 0
        {
            const float mx = fabsf(0.5f * s0x - 0.5f * n0xre) + 1e-7f;
            const float my = fabsf(0.5f * s0y - 0.5f * n0yre) + 1e-7f;
            accum(mx, my, sd2, sy2, slg);
        }
        const float z0xre = s0x, z0xim = 0.f, z0yre = s0y, z0yim = 0.f;
        EMIT(z0, n0, n1);   // W[1]
        EMIT(n0, n1, n2);   // W[2]
        EMIT(n1, n2, n3);   // W[3]
        SHIFT_H             // h2 = X[3], h1 = X[4]
    }

    // ---- chunks c = 1..NCH-1: bins 4c+1..4c+4 (invariant: h2=X[4c-1], h1=X[4c])
#pragma unroll 1
    for (int c = 1; c < NCH; ++c) {
        asm volatile("" ::: "memory");   // block LICM/CSE of LDS loads across chunks
        COEF4(STEP * (float)(4 * c))
        BIN4_DECL
        KLOOP()
        BIN4_EPI
        EMIT(h2, h1, n0);   // W[4c]
        EMIT(h1, n0, n1);   // W[4c+1]
        EMIT(n0, n1, n2);   // W[4c+2]
        EMIT(n1, n2, n3);   // W[4c+3]
        SHIFT_H
    }

    // ---- final bin: W[N/2] = 0.5*X[N/2] - 0.5*Re(X[N/2-1]); im = 0.5*X[N/2]im (~0)
    {
        const float wxre = 0.5f * h1xre - 0.5f * h2xre;
        const float wxim = 0.5f * h1xim;
        const float wyre = 0.5f * h1yre - 0.5f * h2yre;
        const float wyim = 0.5f * h1yim;
        const float mx = sqrtf(fmaf(wxre, wxre, wxim * wxim)) + 1e-7f;
        const float my = sqrtf(fmaf(wyre, wyre, wyim * wyim)) + 1e-7f;
        accum(mx, my, sd2, sy2, slg);
    }

    // ---- reduce: wave shuffle -> LDS -> 3 atomics per block
#pragma unroll
    for (int off = 32; off > 0; off >>= 1) {
        sd2 += __shfl_down(sd2, off);
        sy2 += __shfl_down(sy2, off);
        slg += __shfl_down(slg, off);
    }
    const int wid  = tid >> 6;
    const int lane = tid & 63;
    if (lane == 0) { red[0][wid] = sd2; red[1][wid] = sy2; red[2][wid] = slg; }
    __syncthreads();
    if (tid == 0) {
        atomicAdd(&acc[0],   red[0][0] + red[0][1] + red[0][2] + red[0][3]);
        atomicAdd(&acc[64],  red[1][0] + red[1][1] + red[1][2] + red[1][3]);
        atomicAdd(&acc[128], red[2][0] + red[2][1] + red[2][2] + red[2][3]);
    }
}

__global__ void finalize_kernel(const float* __restrict__ acc,
                                float* __restrict__ out)
{
    if (threadIdx.x == 0 && blockIdx.x == 0) {
        const float nel[4] = {10506240.f, 9474048.f, 8982528.f, 8785920.f};
        float sc = 0.f, mg = 0.f;
#pragma unroll
        for (int r = 0; r < 4; ++r) {
            const float a0 = acc[(r * 3 + 0) * 64];
            const float a1 = acc[(r * 3 + 1) * 64];
            const float a2 = acc[(r * 3 + 2) * 64];
            sc += sqrtf(a0) / (sqrtf(a1) + 1e-8f);
            mg += a2 / nel[r];
        }
        out[0] = sc * 0.25f;
        out[1] = mg * 0.25f;
    }
}

extern "C" void kernel_launch(void* const* d_in, const int* in_sizes, int n_in,
                              void* d_out, int out_size, void* d_ws, size_t ws_size,
                              hipStream_t stream)
{
    const float* x = (const float*)d_in[0];
    const float* y = (const float*)d_in[1];
    float* out = (float*)d_out;
    float* acc = (float*)d_ws;   // 12 accumulators, 64-float (256 B) stride

    hipMemsetAsync(acc, 0, 12 * 64 * sizeof(float), stream);

    stft_loss_kernel<8> <<<16 * 513, 256, 0, stream>>>(x, y, acc + 0 * 192);
    stft_loss_kernel<16><<<16 * 257, 256, 0, stream>>>(x, y, acc + 1 * 192);
    stft_loss_kernel<32><<<16 * 129, 256, 0, stream>>>(x, y, acc + 2 * 192);
    stft_loss_kernel<64><<<16 * 65,  256, 0, stream>>>(x, y, acc + 3 * 192);

    finalize_kernel<<<1, 64, 0, stream>>>(acc, out);
}